// Round 4
// baseline (3078.136 us; speedup 1.0000x reference)
//
#include <hip/hip_runtime.h>
#include <math.h>

#define NN 50000
#define EE 600000
#define CD 128
#define FD 512
#define NCF 6400000.0   // NN*CD as double

__device__ __forceinline__ float4 ld4(const float* p){ return *(const float4*)p; }

// ---------------- GEMM: q,k,v,skip = x @ {Wq,Wk,Wv,Wskip} + bias ----------------
// BM=128 rows, BN=128 cols, BK=32, 256 threads, 8x8 register tile.
__global__ __launch_bounds__(256) void qkvs_gemm(
    const float* __restrict__ x,
    const float* __restrict__ Wq, const float* __restrict__ bq,
    const float* __restrict__ Wk, const float* __restrict__ bk,
    const float* __restrict__ Wv, const float* __restrict__ bv,
    const float* __restrict__ Wsk, const float* __restrict__ bsk,
    float* __restrict__ oq, float* __restrict__ okk,
    float* __restrict__ ov, float* __restrict__ osk)
{
    __shared__ float ast[32*132];   // x tile transposed: [k][row]
    __shared__ float bst[32*132];   // W tile: [k][col]
    const int tid = threadIdx.x;
    const int r0 = blockIdx.x * 128;
    const float* W; const float* bias; float* out;
    switch (blockIdx.y) {
        case 0:  W = Wq;  bias = bq;  out = oq;  break;
        case 1:  W = Wk;  bias = bk;  out = okk; break;
        case 2:  W = Wv;  bias = bv;  out = ov;  break;
        default: W = Wsk; bias = bsk; out = osk; break;
    }
    const int tc = tid & 15, tr = tid >> 4;
    float acc[8][8];
    #pragma unroll
    for (int i = 0; i < 8; ++i)
        #pragma unroll
        for (int j = 0; j < 8; ++j) acc[i][j] = 0.f;

    for (int kc = 0; kc < 4; ++kc) {
        #pragma unroll
        for (int it = 0; it < 4; ++it) {
            int chunk = it*256 + tid;
            int row = chunk >> 3, c4 = chunk & 7;
            float4 g = make_float4(0.f,0.f,0.f,0.f);
            if (r0 + row < NN) g = ld4(&x[(r0+row)*CD + kc*32 + c4*4]);
            ast[(c4*4+0)*132 + row] = g.x;
            ast[(c4*4+1)*132 + row] = g.y;
            ast[(c4*4+2)*132 + row] = g.z;
            ast[(c4*4+3)*132 + row] = g.w;
        }
        #pragma unroll
        for (int it = 0; it < 4; ++it) {
            int chunk = it*256 + tid;
            int kr = chunk >> 5, c4 = chunk & 31;
            *(float4*)&bst[kr*132 + c4*4] = ld4(&W[(kc*32+kr)*CD + c4*4]);
        }
        __syncthreads();
        #pragma unroll
        for (int k = 0; k < 32; ++k) {
            float4 a0 = *(float4*)&ast[k*132 + tr*8];
            float4 a1 = *(float4*)&ast[k*132 + tr*8 + 4];
            float4 b0 = *(float4*)&bst[k*132 + tc*8];
            float4 b1 = *(float4*)&bst[k*132 + tc*8 + 4];
            float ar[8] = {a0.x,a0.y,a0.z,a0.w,a1.x,a1.y,a1.z,a1.w};
            float br[8] = {b0.x,b0.y,b0.z,b0.w,b1.x,b1.y,b1.z,b1.w};
            #pragma unroll
            for (int i = 0; i < 8; ++i)
                #pragma unroll
                for (int j = 0; j < 8; ++j)
                    acc[i][j] += ar[i]*br[j];
        }
        __syncthreads();
    }
    float bcol[8];
    #pragma unroll
    for (int j = 0; j < 8; ++j) bcol[j] = bias[tc*8+j];
    #pragma unroll
    for (int i = 0; i < 8; ++i) {
        int row = r0 + tr*8 + i;
        if (row < NN) {
            float4 o0 = make_float4(acc[i][0]+bcol[0], acc[i][1]+bcol[1],
                                    acc[i][2]+bcol[2], acc[i][3]+bcol[3]);
            float4 o1 = make_float4(acc[i][4]+bcol[4], acc[i][5]+bcol[5],
                                    acc[i][6]+bcol[6], acc[i][7]+bcol[7]);
            *(float4*)&out[row*CD + tc*8]     = o0;
            *(float4*)&out[row*CD + tc*8 + 4] = o1;
        }
    }
}

// ---------------- Edge kernel: e = ea@We fused with attention ----------------
// 128 edges/block. After the e-GEMM, acc[i][j] holds e[edge tr*8+i][col tc*8+j].
// Head of cols tc*8..tc*8+7 is tc>>2 (8 cols lie within one 32-col head).
__global__ __launch_bounds__(256) void edge_kernel(
    const float* __restrict__ ea, const int* __restrict__ ei,
    const float* __restrict__ We,
    const float* __restrict__ q, const float* __restrict__ kmat, const float* __restrict__ vmat,
    float* __restrict__ oa, float* __restrict__ ss)
{
    __shared__ float ast[32*132];
    __shared__ float bst[32*132];
    __shared__ int sidx[128];
    __shared__ int didx[128];
    const int tid = threadIdx.x;
    const int e0 = blockIdx.x * 128;
    const int ne = min(128, EE - e0);
    if (tid < 128) {
        sidx[tid] = (tid < ne) ? ei[e0 + tid] : 0;
    } else {
        int le = tid - 128;
        didx[le] = (le < ne) ? ei[EE + e0 + le] : 0;
    }
    const int tc = tid & 15, tr = tid >> 4;
    float acc[8][8];
    #pragma unroll
    for (int i = 0; i < 8; ++i)
        #pragma unroll
        for (int j = 0; j < 8; ++j) acc[i][j] = 0.f;

    for (int kc = 0; kc < 4; ++kc) {
        #pragma unroll
        for (int it = 0; it < 4; ++it) {
            int chunk = it*256 + tid;
            int le = chunk >> 3, c4 = chunk & 7;
            float4 g = make_float4(0.f,0.f,0.f,0.f);
            if (le < ne) g = ld4(&ea[(size_t)(e0+le)*CD + kc*32 + c4*4]);
            ast[(c4*4+0)*132 + le] = g.x;
            ast[(c4*4+1)*132 + le] = g.y;
            ast[(c4*4+2)*132 + le] = g.z;
            ast[(c4*4+3)*132 + le] = g.w;
        }
        #pragma unroll
        for (int it = 0; it < 4; ++it) {
            int chunk = it*256 + tid;
            int kr = chunk >> 5, c4 = chunk & 31;
            *(float4*)&bst[kr*132 + c4*4] = ld4(&We[(kc*32+kr)*CD + c4*4]);
        }
        __syncthreads();
        #pragma unroll
        for (int k = 0; k < 32; ++k) {
            float4 a0 = *(float4*)&ast[k*132 + tr*8];
            float4 a1 = *(float4*)&ast[k*132 + tr*8 + 4];
            float4 b0 = *(float4*)&bst[k*132 + tc*8];
            float4 b1 = *(float4*)&bst[k*132 + tc*8 + 4];
            float ar[8] = {a0.x,a0.y,a0.z,a0.w,a1.x,a1.y,a1.z,a1.w};
            float br[8] = {b0.x,b0.y,b0.z,b0.w,b1.x,b1.y,b1.z,b1.w};
            #pragma unroll
            for (int i = 0; i < 8; ++i)
                #pragma unroll
                for (int j = 0; j < 8; ++j)
                    acc[i][j] += ar[i]*br[j];
        }
        __syncthreads();
    }
    // ---- attention phase: no segment-max needed (exp(alpha) safely < ~3000) ----
    const int head = tc >> 2;
    const float inv_sqrt_o = 0.17677669529663687f;  // 1/sqrt(32)
    #pragma unroll
    for (int i = 0; i < 8; ++i) {
        int le = tr*8 + i;
        if (le < ne) {
            int sn = sidx[le], dn = didx[le];
            const float* qp = q    + dn*CD + tc*8;
            const float* kp = kmat + sn*CD + tc*8;
            const float* vp = vmat + sn*CD + tc*8;
            float4 qa = ld4(qp), qb = ld4(qp+4);
            float4 ka = ld4(kp), kb = ld4(kp+4);
            float4 va = ld4(vp), vb = ld4(vp+4);
            float p =
                qa.x*(ka.x+acc[i][0]) + qa.y*(ka.y+acc[i][1]) +
                qa.z*(ka.z+acc[i][2]) + qa.w*(ka.w+acc[i][3]) +
                qb.x*(kb.x+acc[i][4]) + qb.y*(kb.y+acc[i][5]) +
                qb.z*(kb.z+acc[i][6]) + qb.w*(kb.w+acc[i][7]);
            // sum over the 4 threads (tc bits 0-1) sharing this (edge, head)
            p += __shfl_xor(p, 1);
            p += __shfl_xor(p, 2);
            float a = expf(p * inv_sqrt_o);
            if ((tc & 3) == 0) atomicAdd(&ss[dn*4 + head], a);
            float* op = oa + dn*CD + tc*8;
            atomicAdd(op+0, a*(va.x+acc[i][0]));
            atomicAdd(op+1, a*(va.y+acc[i][1]));
            atomicAdd(op+2, a*(va.z+acc[i][2]));
            atomicAdd(op+3, a*(va.w+acc[i][3]));
            atomicAdd(op+4, a*(vb.x+acc[i][4]));
            atomicAdd(op+5, a*(vb.y+acc[i][5]));
            atomicAdd(op+6, a*(vb.z+acc[i][6]));
            atomicAdd(op+7, a*(vb.w+acc[i][7]));
        }
    }
}

// ---------------- combine: normalize, beta-gate, residual, LN1 stats ----------------
__global__ __launch_bounds__(256) void combine_kernel(
    const float* __restrict__ x, const float* __restrict__ xr,
    const float* __restrict__ oa, const float* __restrict__ ss,
    const float* __restrict__ Wbeta, float* __restrict__ y, double* __restrict__ red)
{
    const int lane = threadIdx.x & 63;
    const int wid = blockIdx.x*4 + (threadIdx.x >> 6);
    const int nw = gridDim.x*4;
    const int c0 = lane, c1 = lane + 64;
    const float wb_o0 = Wbeta[c0],     wb_o1 = Wbeta[c1];
    const float wb_x0 = Wbeta[128+c0], wb_x1 = Wbeta[128+c1];
    const float wb_d0 = Wbeta[256+c0], wb_d1 = Wbeta[256+c1];
    float lsum = 0.f, lsq = 0.f;
    for (int n = wid; n < NN; n += nw) {
        float s0 = ss[n*4 + (c0>>5)] + 1e-16f;
        float s1 = ss[n*4 + 2 + (lane>>5)] + 1e-16f;
        float o0 = oa[n*CD+c0] / s0;
        float o1 = oa[n*CD+c1] / s1;
        float r0v = xr[n*CD+c0], r1v = xr[n*CD+c1];
        float d = o0*wb_o0 + r0v*wb_x0 + (o0-r0v)*wb_d0
                + o1*wb_o1 + r1v*wb_x1 + (o1-r1v)*wb_d1;
        #pragma unroll
        for (int off = 32; off; off >>= 1) d += __shfl_xor(d, off);
        float beta = 1.0f / (1.0f + expf(-d));
        float y0 = x[n*CD+c0] + beta*r0v + (1.0f-beta)*o0;
        float y1 = x[n*CD+c1] + beta*r1v + (1.0f-beta)*o1;
        y[n*CD+c0] = y0; y[n*CD+c1] = y1;
        lsum += y0 + y1; lsq += y0*y0 + y1*y1;
    }
    #pragma unroll
    for (int off = 32; off; off >>= 1) {
        lsum += __shfl_xor(lsum, off);
        lsq  += __shfl_xor(lsq,  off);
    }
    if (lane == 0) {
        atomicAdd(&red[0], (double)lsum);
        atomicAdd(&red[1], (double)lsq);
    }
}

// ---------------- FFN1: LN1(y) @ W1 + bf1, exact gelu -> h ----------------
__global__ __launch_bounds__(256) void ffn1_gemm(
    const float* __restrict__ y, const float* __restrict__ W1, const float* __restrict__ bf1,
    const float* __restrict__ lng, const float* __restrict__ lnb,
    const double* __restrict__ red, float* __restrict__ h)
{
    __shared__ float ast[32*132];
    __shared__ float bst[32*132];
    const int tid = threadIdx.x;
    const int r0 = blockIdx.x * 128;
    const int cb = blockIdx.y;
    double m = red[0] * (1.0/NCF);
    double var = red[1] * (1.0/NCF) - m*m;
    if (var < 0.0) var = 0.0;
    const float mean = (float)m;
    const float scale = (float)(1.0 / (sqrt(var) + 1e-5));
    const int tc = tid & 15, tr = tid >> 4;
    float acc[8][8];
    #pragma unroll
    for (int i = 0; i < 8; ++i)
        #pragma unroll
        for (int j = 0; j < 8; ++j) acc[i][j] = 0.f;

    for (int kc = 0; kc < 4; ++kc) {
        #pragma unroll
        for (int it = 0; it < 4; ++it) {
            int chunk = it*256 + tid;
            int row = chunk >> 3, c4 = chunk & 7;
            float4 g = make_float4(0.f,0.f,0.f,0.f);
            if (r0 + row < NN) g = ld4(&y[(r0+row)*CD + kc*32 + c4*4]);
            int col = kc*32 + c4*4;
            g.x = (g.x - mean)*scale*lng[col+0] + lnb[col+0];
            g.y = (g.y - mean)*scale*lng[col+1] + lnb[col+1];
            g.z = (g.z - mean)*scale*lng[col+2] + lnb[col+2];
            g.w = (g.w - mean)*scale*lng[col+3] + lnb[col+3];
            ast[(c4*4+0)*132 + row] = g.x;
            ast[(c4*4+1)*132 + row] = g.y;
            ast[(c4*4+2)*132 + row] = g.z;
            ast[(c4*4+3)*132 + row] = g.w;
        }
        #pragma unroll
        for (int it = 0; it < 4; ++it) {
            int chunk = it*256 + tid;
            int kr = chunk >> 5, c4 = chunk & 31;
            *(float4*)&bst[kr*132 + c4*4] = ld4(&W1[(size_t)(kc*32+kr)*FD + cb*128 + c4*4]);
        }
        __syncthreads();
        #pragma unroll
        for (int k = 0; k < 32; ++k) {
            float4 a0 = *(float4*)&ast[k*132 + tr*8];
            float4 a1 = *(float4*)&ast[k*132 + tr*8 + 4];
            float4 b0 = *(float4*)&bst[k*132 + tc*8];
            float4 b1 = *(float4*)&bst[k*132 + tc*8 + 4];
            float ar[8] = {a0.x,a0.y,a0.z,a0.w,a1.x,a1.y,a1.z,a1.w};
            float br[8] = {b0.x,b0.y,b0.z,b0.w,b1.x,b1.y,b1.z,b1.w};
            #pragma unroll
            for (int i = 0; i < 8; ++i)
                #pragma unroll
                for (int j = 0; j < 8; ++j)
                    acc[i][j] += ar[i]*br[j];
        }
        __syncthreads();
    }
    float bcol[8];
    #pragma unroll
    for (int j = 0; j < 8; ++j) bcol[j] = bf1[cb*128 + tc*8 + j];
    #pragma unroll
    for (int i = 0; i < 8; ++i) {
        int row = r0 + tr*8 + i;
        if (row < NN) {
            float o[8];
            #pragma unroll
            for (int j = 0; j < 8; ++j) {
                float hv = acc[i][j] + bcol[j];
                o[j] = 0.5f*hv*(1.0f + erff(hv*0.7071067811865476f));
            }
            float4 o0 = make_float4(o[0],o[1],o[2],o[3]);
            float4 o1 = make_float4(o[4],o[5],o[6],o[7]);
            *(float4*)&h[(size_t)row*FD + cb*128 + tc*8]     = o0;
            *(float4*)&h[(size_t)row*FD + cb*128 + tc*8 + 4] = o1;
        }
    }
}

// ---------------- FFN2: h @ W2 + bf2 + LN1(y), LN2 stats -> d_out ----------------
__global__ __launch_bounds__(256) void ffn2_gemm(
    const float* __restrict__ h, const float* __restrict__ W2, const float* __restrict__ bf2,
    const float* __restrict__ y, const float* __restrict__ lng, const float* __restrict__ lnb,
    double* __restrict__ red, float* __restrict__ outz)
{
    __shared__ float ast[32*132];
    __shared__ float bst[32*132];
    const int tid = threadIdx.x;
    const int r0 = blockIdx.x * 128;
    double m = red[0] * (1.0/NCF);
    double var = red[1] * (1.0/NCF) - m*m;
    if (var < 0.0) var = 0.0;
    const float mean = (float)m;
    const float scale = (float)(1.0 / (sqrt(var) + 1e-5));
    const int tc = tid & 15, tr = tid >> 4;
    float acc[8][8];
    #pragma unroll
    for (int i = 0; i < 8; ++i)
        #pragma unroll
        for (int j = 0; j < 8; ++j) acc[i][j] = 0.f;

    for (int kc = 0; kc < 16; ++kc) {
        #pragma unroll
        for (int it = 0; it < 4; ++it) {
            int chunk = it*256 + tid;
            int row = chunk >> 3, c4 = chunk & 7;
            float4 g = make_float4(0.f,0.f,0.f,0.f);
            if (r0 + row < NN) g = ld4(&h[(size_t)(r0+row)*FD + kc*32 + c4*4]);
            ast[(c4*4+0)*132 + row] = g.x;
            ast[(c4*4+1)*132 + row] = g.y;
            ast[(c4*4+2)*132 + row] = g.z;
            ast[(c4*4+3)*132 + row] = g.w;
        }
        #pragma unroll
        for (int it = 0; it < 4; ++it) {
            int chunk = it*256 + tid;
            int kr = chunk >> 5, c4 = chunk & 31;
            *(float4*)&bst[kr*132 + c4*4] = ld4(&W2[(size_t)(kc*32+kr)*CD + c4*4]);
        }
        __syncthreads();
        #pragma unroll
        for (int k = 0; k < 32; ++k) {
            float4 a0 = *(float4*)&ast[k*132 + tr*8];
            float4 a1 = *(float4*)&ast[k*132 + tr*8 + 4];
            float4 b0 = *(float4*)&bst[k*132 + tc*8];
            float4 b1 = *(float4*)&bst[k*132 + tc*8 + 4];
            float ar[8] = {a0.x,a0.y,a0.z,a0.w,a1.x,a1.y,a1.z,a1.w};
            float br[8] = {b0.x,b0.y,b0.z,b0.w,b1.x,b1.y,b1.z,b1.w};
            #pragma unroll
            for (int i = 0; i < 8; ++i)
                #pragma unroll
                for (int j = 0; j < 8; ++j)
                    acc[i][j] += ar[i]*br[j];
        }
        __syncthreads();
    }
    float g1c[8], b1c[8], bfc[8];
    #pragma unroll
    for (int j = 0; j < 8; ++j) {
        int col = tc*8 + j;
        g1c[j] = lng[col]; b1c[j] = lnb[col]; bfc[j] = bf2[col];
    }
    float lsum = 0.f, lsq = 0.f;
    #pragma unroll
    for (int i = 0; i < 8; ++i) {
        int row = r0 + tr*8 + i;
        if (row < NN) {
            float4 ya = ld4(&y[row*CD + tc*8]);
            float4 yb = ld4(&y[row*CD + tc*8 + 4]);
            float yv[8] = {ya.x,ya.y,ya.z,ya.w,yb.x,yb.y,yb.z,yb.w};
            float z[8];
            #pragma unroll
            for (int j = 0; j < 8; ++j) {
                float x1 = (yv[j] - mean)*scale*g1c[j] + b1c[j];
                z[j] = acc[i][j] + bfc[j] + x1;
                lsum += z[j]; lsq += z[j]*z[j];
            }
            float4 z0 = make_float4(z[0],z[1],z[2],z[3]);
            float4 z1 = make_float4(z[4],z[5],z[6],z[7]);
            *(float4*)&outz[row*CD + tc*8]     = z0;
            *(float4*)&outz[row*CD + tc*8 + 4] = z1;
        }
    }
    #pragma unroll
    for (int off = 32; off; off >>= 1) {
        lsum += __shfl_xor(lsum, off);
        lsq  += __shfl_xor(lsq,  off);
    }
    if ((threadIdx.x & 63) == 0) {
        atomicAdd(&red[2], (double)lsum);
        atomicAdd(&red[3], (double)lsq);
    }
}

// ---------------- LN2 in-place on d_out ----------------
__global__ __launch_bounds__(256) void ln2_kernel(
    float* __restrict__ z, const float* __restrict__ g2, const float* __restrict__ b2,
    const double* __restrict__ red)
{
    double m = red[2] * (1.0/NCF);
    double var = red[3] * (1.0/NCF) - m*m;
    if (var < 0.0) var = 0.0;
    const float mean = (float)m;
    const float scale = (float)(1.0 / (sqrt(var) + 1e-5));
    const int stride = gridDim.x * blockDim.x;
    for (int i = blockIdx.x*blockDim.x + threadIdx.x; i < NN*32; i += stride) {
        int c4 = (i & 31) * 4;
        float4 zv = *(float4*)&z[(size_t)i*4];
        float4 gv = ld4(&g2[c4]);
        float4 bv = ld4(&b2[c4]);
        zv.x = (zv.x - mean)*scale*gv.x + bv.x;
        zv.y = (zv.y - mean)*scale*gv.y + bv.y;
        zv.z = (zv.z - mean)*scale*gv.z + bv.z;
        zv.w = (zv.w - mean)*scale*gv.w + bv.w;
        *(float4*)&z[(size_t)i*4] = zv;
    }
}

extern "C" void kernel_launch(void* const* d_in, const int* in_sizes, int n_in,
                              void* d_out, int out_size, void* d_ws, size_t ws_size,
                              hipStream_t stream) {
    const float* x     = (const float*)d_in[0];
    const float* ea    = (const float*)d_in[1];
    const int*   ei    = (const int*)d_in[2];      // harness passes integers as int32
    const float* Wq    = (const float*)d_in[3];
    const float* bq    = (const float*)d_in[4];
    const float* Wk    = (const float*)d_in[5];
    const float* bk    = (const float*)d_in[6];
    const float* Wv    = (const float*)d_in[7];
    const float* bv    = (const float*)d_in[8];
    const float* We    = (const float*)d_in[9];
    const float* Wsk   = (const float*)d_in[10];
    const float* bsk   = (const float*)d_in[11];
    const float* Wbeta = (const float*)d_in[12];
    const float* g1v   = (const float*)d_in[13];
    const float* be1   = (const float*)d_in[14];
    const float* g2v   = (const float*)d_in[15];
    const float* be2   = (const float*)d_in[16];
    const float* W1    = (const float*)d_in[17];
    const float* bf1   = (const float*)d_in[18];
    const float* W2    = (const float*)d_in[19];
    const float* bf2   = (const float*)d_in[20];

    float* wsf = (float*)d_ws;
    float* q   = wsf;                 // N*128, later reused as y
    float* kk  = wsf + 6400000;       // N*128, reused as part of h (N*512)
    float* vv  = wsf + 12800000;      // N*128, reused as part of h
    float* xr  = wsf + 19200000;      // N*128, reused as part of h
    float* oa  = wsf + 25600000;      // N*128, reused as part of h
    float* ss  = wsf + 32000000;      // N*4
    double* red = (double*)(wsf + 32200000);  // 4 doubles
    float* y = q;
    float* h = kk;                    // h spans kk..oa (N*512 floats)
    float* zout = (float*)d_out;

    (void)hipMemsetAsync(oa, 0, (size_t)6400000*4, stream);   // oa: N*128 floats
    (void)hipMemsetAsync(ss, 0, (size_t)200000*4 + 32, stream); // ss + red

    dim3 gA((NN + 127)/128, 4);
    qkvs_gemm<<<gA, 256, 0, stream>>>(x, Wq,bq, Wk,bk, Wv,bv, Wsk,bsk, q, kk, vv, xr);

    edge_kernel<<<(EE + 127)/128, 256, 0, stream>>>(ea, ei, We, q, kk, vv, oa, ss);

    combine_kernel<<<1024, 256, 0, stream>>>(x, xr, oa, ss, Wbeta, y, red);

    dim3 gF((NN + 127)/128, 4);
    ffn1_gemm<<<gF, 256, 0, stream>>>(y, W1, bf1, g1v, be1, red, h);

    ffn2_gemm<<<(NN + 127)/128, 256, 0, stream>>>(h, W2, bf2, y, g1v, be1, red, zout);

    ln2_kernel<<<2048, 256, 0, stream>>>(zout, g2v, be2, red);
}

// Round 7
// 1614.138 us; speedup vs baseline: 1.9070x; 1.9070x over previous
//
#include <hip/hip_runtime.h>
#include <math.h>

#define NN 50000
#define EE 600000
#define CD 128
#define FD 512
#define NCF 6400000.0   // NN*CD as double

__device__ __forceinline__ float4 ld4(const float* p){ return *(const float4*)p; }

// ---------------- GEMM: q,k,v,skip = x @ {Wq,Wk,Wv,Wskip} + bias ----------------
__global__ __launch_bounds__(256) void qkvs_gemm(
    const float* __restrict__ x,
    const float* __restrict__ Wq, const float* __restrict__ bq,
    const float* __restrict__ Wk, const float* __restrict__ bk,
    const float* __restrict__ Wv, const float* __restrict__ bv,
    const float* __restrict__ Wsk, const float* __restrict__ bsk,
    float* __restrict__ oq, float* __restrict__ okk,
    float* __restrict__ ov, float* __restrict__ osk)
{
    __shared__ float ast[32*132];
    __shared__ float bst[32*132];
    const int tid = threadIdx.x;
    const int r0 = blockIdx.x * 128;
    const float* W; const float* bias; float* out;
    switch (blockIdx.y) {
        case 0:  W = Wq;  bias = bq;  out = oq;  break;
        case 1:  W = Wk;  bias = bk;  out = okk; break;
        case 2:  W = Wv;  bias = bv;  out = ov;  break;
        default: W = Wsk; bias = bsk; out = osk; break;
    }
    const int tc = tid & 15, tr = tid >> 4;
    float acc[8][8];
    #pragma unroll
    for (int i = 0; i < 8; ++i)
        #pragma unroll
        for (int j = 0; j < 8; ++j) acc[i][j] = 0.f;

    for (int kc = 0; kc < 4; ++kc) {
        #pragma unroll
        for (int it = 0; it < 4; ++it) {
            int chunk = it*256 + tid;
            int row = chunk >> 3, c4 = chunk & 7;
            float4 g = make_float4(0.f,0.f,0.f,0.f);
            if (r0 + row < NN) g = ld4(&x[(r0+row)*CD + kc*32 + c4*4]);
            ast[(c4*4+0)*132 + row] = g.x;
            ast[(c4*4+1)*132 + row] = g.y;
            ast[(c4*4+2)*132 + row] = g.z;
            ast[(c4*4+3)*132 + row] = g.w;
        }
        #pragma unroll
        for (int it = 0; it < 4; ++it) {
            int chunk = it*256 + tid;
            int kr = chunk >> 5, c4 = chunk & 31;
            *(float4*)&bst[kr*132 + c4*4] = ld4(&W[(kc*32+kr)*CD + c4*4]);
        }
        __syncthreads();
        #pragma unroll
        for (int k = 0; k < 32; ++k) {
            float4 a0 = *(float4*)&ast[k*132 + tr*8];
            float4 a1 = *(float4*)&ast[k*132 + tr*8 + 4];
            float4 b0 = *(float4*)&bst[k*132 + tc*8];
            float4 b1 = *(float4*)&bst[k*132 + tc*8 + 4];
            float ar[8] = {a0.x,a0.y,a0.z,a0.w,a1.x,a1.y,a1.z,a1.w};
            float br[8] = {b0.x,b0.y,b0.z,b0.w,b1.x,b1.y,b1.z,b1.w};
            #pragma unroll
            for (int i = 0; i < 8; ++i)
                #pragma unroll
                for (int j = 0; j < 8; ++j)
                    acc[i][j] += ar[i]*br[j];
        }
        __syncthreads();
    }
    float bcol[8];
    #pragma unroll
    for (int j = 0; j < 8; ++j) bcol[j] = bias[tc*8+j];
    #pragma unroll
    for (int i = 0; i < 8; ++i) {
        int row = r0 + tr*8 + i;
        if (row < NN) {
            float4 o0 = make_float4(acc[i][0]+bcol[0], acc[i][1]+bcol[1],
                                    acc[i][2]+bcol[2], acc[i][3]+bcol[3]);
            float4 o1 = make_float4(acc[i][4]+bcol[4], acc[i][5]+bcol[5],
                                    acc[i][6]+bcol[6], acc[i][7]+bcol[7]);
            *(float4*)&out[row*CD + tc*8]     = o0;
            *(float4*)&out[row*CD + tc*8 + 4] = o1;
        }
    }
}

// ---------------- CSR build ----------------
__global__ __launch_bounds__(256) void hist_kernel(const int* __restrict__ ei, int* __restrict__ cnt)
{
    int j = blockIdx.x*blockDim.x + threadIdx.x;
    if (j < EE) atomicAdd(&cnt[ei[EE + j]], 1);
}

// 1 block, 256 threads: exclusive scan of cnt -> off[0..NN], cursor copy into cnt
__global__ __launch_bounds__(256) void scan_kernel(int* __restrict__ cnt, int* __restrict__ off)
{
    __shared__ int part[256];
    const int t = threadIdx.x;
    const int nper = (NN + 255) / 256;     // 196
    const int lo = t*nper, hi = min(lo + nper, NN);
    int ssum = 0;
    for (int i = lo; i < hi; ++i) ssum += cnt[i];
    part[t] = ssum;
    __syncthreads();
    if (t == 0) {
        int run = 0;
        for (int i = 0; i < 256; ++i) { int tmp = part[i]; part[i] = run; run += tmp; }
    }
    __syncthreads();
    int run = part[t];
    for (int i = lo; i < hi; ++i) {
        int c = cnt[i];
        off[i] = run;
        cnt[i] = run;      // cursor for scatter
        run += c;
    }
    if (hi == NN) off[NN] = run;
}

__global__ __launch_bounds__(256) void scatter_kernel(
    const int* __restrict__ ei, int* __restrict__ cur, int* __restrict__ elist)
{
    int j = blockIdx.x*blockDim.x + threadIdx.x;
    if (j < EE) {
        int pos = atomicAdd(&cur[ei[EE + j]], 1);
        elist[pos] = j;
    }
}

// ---------------- Alpha kernel: e = ea@We (tiled), alpha, a = exp -> a4 ----------------
__global__ __launch_bounds__(256) void alpha_kernel(
    const float* __restrict__ ea, const int* __restrict__ ei,
    const float* __restrict__ We,
    const float* __restrict__ q, const float* __restrict__ kmat,
    float* __restrict__ aout)
{
    __shared__ float ast[32*132];
    __shared__ float bst[32*132];
    __shared__ int sidx[128];
    __shared__ int didx[128];
    const int tid = threadIdx.x;
    const int e0 = blockIdx.x * 128;
    const int ne = min(128, EE - e0);
    if (tid < 128) {
        sidx[tid] = (tid < ne) ? ei[e0 + tid] : 0;
    } else {
        int le = tid - 128;
        didx[le] = (le < ne) ? ei[EE + e0 + le] : 0;
    }
    const int tc = tid & 15, tr = tid >> 4;
    float acc[8][8];
    #pragma unroll
    for (int i = 0; i < 8; ++i)
        #pragma unroll
        for (int j = 0; j < 8; ++j) acc[i][j] = 0.f;

    for (int kc = 0; kc < 4; ++kc) {
        #pragma unroll
        for (int it = 0; it < 4; ++it) {
            int chunk = it*256 + tid;
            int le = chunk >> 3, c4 = chunk & 7;
            float4 g = make_float4(0.f,0.f,0.f,0.f);
            if (le < ne) g = ld4(&ea[(size_t)(e0+le)*CD + kc*32 + c4*4]);
            ast[(c4*4+0)*132 + le] = g.x;
            ast[(c4*4+1)*132 + le] = g.y;
            ast[(c4*4+2)*132 + le] = g.z;
            ast[(c4*4+3)*132 + le] = g.w;
        }
        #pragma unroll
        for (int it = 0; it < 4; ++it) {
            int chunk = it*256 + tid;
            int kr = chunk >> 5, c4 = chunk & 31;
            *(float4*)&bst[kr*132 + c4*4] = ld4(&We[(kc*32+kr)*CD + c4*4]);
        }
        __syncthreads();
        #pragma unroll
        for (int k = 0; k < 32; ++k) {
            float4 a0 = *(float4*)&ast[k*132 + tr*8];
            float4 a1 = *(float4*)&ast[k*132 + tr*8 + 4];
            float4 b0 = *(float4*)&bst[k*132 + tc*8];
            float4 b1 = *(float4*)&bst[k*132 + tc*8 + 4];
            float ar[8] = {a0.x,a0.y,a0.z,a0.w,a1.x,a1.y,a1.z,a1.w};
            float br[8] = {b0.x,b0.y,b0.z,b0.w,b1.x,b1.y,b1.z,b1.w};
            #pragma unroll
            for (int i = 0; i < 8; ++i)
                #pragma unroll
                for (int j = 0; j < 8; ++j)
                    acc[i][j] += ar[i]*br[j];
        }
        __syncthreads();
    }
    const int head = tc >> 2;
    const float inv_sqrt_o = 0.17677669529663687f;  // 1/sqrt(32)
    #pragma unroll
    for (int i = 0; i < 8; ++i) {
        int le = tr*8 + i;
        if (le < ne) {
            int sn = sidx[le], dn = didx[le];
            const float* qp = q    + dn*CD + tc*8;
            const float* kp = kmat + sn*CD + tc*8;
            float4 qa = ld4(qp), qb = ld4(qp+4);
            float4 ka = ld4(kp), kb = ld4(kp+4);
            float p =
                qa.x*(ka.x+acc[i][0]) + qa.y*(ka.y+acc[i][1]) +
                qa.z*(ka.z+acc[i][2]) + qa.w*(ka.w+acc[i][3]) +
                qb.x*(kb.x+acc[i][4]) + qb.y*(kb.y+acc[i][5]) +
                qb.z*(kb.z+acc[i][6]) + qb.w*(kb.w+acc[i][7]);
            p += __shfl_xor(p, 1);
            p += __shfl_xor(p, 2);
            float a = expf(p * inv_sqrt_o);
            if ((tc & 3) == 0) aout[(size_t)(e0+le)*4 + head] = a;
        }
    }
}

// ---------------- Node kernel: per-dst aggregation, zero f32 atomics ----------------
// out[n,d] = (sum_j a_{j,h(d)} v[src_j,d] + sum_k s[h(d)][k] We[k,d]) / (den_{h(d)} + 1e-16)
// with s[h][k] = sum_j a_{j,h} ea[j,k]   (linearity through We)
__global__ __launch_bounds__(256) void node_kernel(
    const int* __restrict__ ei, const int* __restrict__ off, const int* __restrict__ elist,
    const float* __restrict__ a4, const float* __restrict__ ea,
    const float* __restrict__ vmat, const float* __restrict__ We,
    float* __restrict__ oa)
{
    __shared__ float s_lds[4][512];
    const int w = threadIdx.x >> 6;
    const int l = threadIdx.x & 63;
    const int n = blockIdx.x * 4 + w;
    if (n >= NN) return;
    const int beg = off[n], end = off[n+1];
    const int hsel = l >> 5;   // head of col l is hsel; head of col l+64 is 2+hsel
    float s0k0=0,s1k0=0,s2k0=0,s3k0=0;
    float s0k1=0,s1k1=0,s2k1=0,s3k1=0;
    float av0=0, av1=0, den0=0, den1=0;
    for (int t = beg; t < end; ++t) {
        int eid = elist[t];
        int src = ei[eid];
        float4 aq = ld4(&a4[(size_t)eid*4]);
        float ea0 = ea[(size_t)eid*CD + l];
        float ea1 = ea[(size_t)eid*CD + 64 + l];
        float v0  = vmat[(size_t)src*CD + l];
        float v1  = vmat[(size_t)src*CD + 64 + l];
        float aH0 = hsel ? aq.y : aq.x;
        float aH1 = hsel ? aq.w : aq.z;
        s0k0 += aq.x*ea0; s1k0 += aq.y*ea0; s2k0 += aq.z*ea0; s3k0 += aq.w*ea0;
        s0k1 += aq.x*ea1; s1k1 += aq.y*ea1; s2k1 += aq.z*ea1; s3k1 += aq.w*ea1;
        av0 += aH0*v0; av1 += aH1*v1;
        den0 += aH0;   den1 += aH1;
    }
    // stage s to this wave's private LDS slab (same-wave RAW: compiler inserts lgkmcnt)
    s_lds[w][0*128 + l] = s0k0;  s_lds[w][0*128 + 64 + l] = s0k1;
    s_lds[w][1*128 + l] = s1k0;  s_lds[w][1*128 + 64 + l] = s1k1;
    s_lds[w][2*128 + l] = s2k0;  s_lds[w][2*128 + 64 + l] = s2k1;
    s_lds[w][3*128 + l] = s3k0;  s_lds[w][3*128 + 64 + l] = s3k1;
    const float* sh0 = &s_lds[w][hsel*128];
    const float* sh1 = &s_lds[w][(2+hsel)*128];
    float oe0 = 0.f, oe1 = 0.f;
    #pragma unroll 4
    for (int k = 0; k < 128; ++k) {
        float w0 = We[k*CD + l];
        float w1 = We[k*CD + 64 + l];
        oe0 += sh0[k] * w0;
        oe1 += sh1[k] * w1;
    }
    oa[(size_t)n*CD + l]      = (av0 + oe0) / (den0 + 1e-16f);
    oa[(size_t)n*CD + 64 + l] = (av1 + oe1) / (den1 + 1e-16f);
}

// ---------------- combine: beta-gate, residual, LN1 stats (oa pre-normalized) ----------------
__global__ __launch_bounds__(256) void combine_kernel(
    const float* __restrict__ x, const float* __restrict__ xr,
    const float* __restrict__ oa,
    const float* __restrict__ Wbeta, float* __restrict__ y, double* __restrict__ red)
{
    const int lane = threadIdx.x & 63;
    const int wid = blockIdx.x*4 + (threadIdx.x >> 6);
    const int nw = gridDim.x*4;
    const int c0 = lane, c1 = lane + 64;
    const float wb_o0 = Wbeta[c0],     wb_o1 = Wbeta[c1];
    const float wb_x0 = Wbeta[128+c0], wb_x1 = Wbeta[128+c1];
    const float wb_d0 = Wbeta[256+c0], wb_d1 = Wbeta[256+c1];
    float lsum = 0.f, lsq = 0.f;
    for (int n = wid; n < NN; n += nw) {
        float o0 = oa[n*CD+c0];
        float o1 = oa[n*CD+c1];
        float r0v = xr[n*CD+c0], r1v = xr[n*CD+c1];
        float d = o0*wb_o0 + r0v*wb_x0 + (o0-r0v)*wb_d0
                + o1*wb_o1 + r1v*wb_x1 + (o1-r1v)*wb_d1;
        #pragma unroll
        for (int off = 32; off; off >>= 1) d += __shfl_xor(d, off);
        float beta = 1.0f / (1.0f + expf(-d));
        float y0 = x[n*CD+c0] + beta*r0v + (1.0f-beta)*o0;
        float y1 = x[n*CD+c1] + beta*r1v + (1.0f-beta)*o1;
        y[n*CD+c0] = y0; y[n*CD+c1] = y1;
        lsum += y0 + y1; lsq += y0*y0 + y1*y1;
    }
    #pragma unroll
    for (int off = 32; off; off >>= 1) {
        lsum += __shfl_xor(lsum, off);
        lsq  += __shfl_xor(lsq,  off);
    }
    if (lane == 0) {
        atomicAdd(&red[0], (double)lsum);
        atomicAdd(&red[1], (double)lsq);
    }
}

// ---------------- FFN1: LN1(y) @ W1 + bf1, exact gelu -> h ----------------
__global__ __launch_bounds__(256) void ffn1_gemm(
    const float* __restrict__ y, const float* __restrict__ W1, const float* __restrict__ bf1,
    const float* __restrict__ lng, const float* __restrict__ lnb,
    const double* __restrict__ red, float* __restrict__ h)
{
    __shared__ float ast[32*132];
    __shared__ float bst[32*132];
    const int tid = threadIdx.x;
    const int r0 = blockIdx.x * 128;
    const int cb = blockIdx.y;
    double m = red[0] * (1.0/NCF);
    double var = red[1] * (1.0/NCF) - m*m;
    if (var < 0.0) var = 0.0;
    const float mean = (float)m;
    const float scale = (float)(1.0 / (sqrt(var) + 1e-5));
    const int tc = tid & 15, tr = tid >> 4;
    float acc[8][8];
    #pragma unroll
    for (int i = 0; i < 8; ++i)
        #pragma unroll
        for (int j = 0; j < 8; ++j) acc[i][j] = 0.f;

    for (int kc = 0; kc < 4; ++kc) {
        #pragma unroll
        for (int it = 0; it < 4; ++it) {
            int chunk = it*256 + tid;
            int row = chunk >> 3, c4 = chunk & 7;
            float4 g = make_float4(0.f,0.f,0.f,0.f);
            if (r0 + row < NN) g = ld4(&y[(r0+row)*CD + kc*32 + c4*4]);
            int col = kc*32 + c4*4;
            g.x = (g.x - mean)*scale*lng[col+0] + lnb[col+0];
            g.y = (g.y - mean)*scale*lng[col+1] + lnb[col+1];
            g.z = (g.z - mean)*scale*lng[col+2] + lnb[col+2];
            g.w = (g.w - mean)*scale*lng[col+3] + lnb[col+3];
            ast[(c4*4+0)*132 + row] = g.x;
            ast[(c4*4+1)*132 + row] = g.y;
            ast[(c4*4+2)*132 + row] = g.z;
            ast[(c4*4+3)*132 + row] = g.w;
        }
        #pragma unroll
        for (int it = 0; it < 4; ++it) {
            int chunk = it*256 + tid;
            int kr = chunk >> 5, c4 = chunk & 31;
            *(float4*)&bst[kr*132 + c4*4] = ld4(&W1[(size_t)(kc*32+kr)*FD + cb*128 + c4*4]);
        }
        __syncthreads();
        #pragma unroll
        for (int k = 0; k < 32; ++k) {
            float4 a0 = *(float4*)&ast[k*132 + tr*8];
            float4 a1 = *(float4*)&ast[k*132 + tr*8 + 4];
            float4 b0 = *(float4*)&bst[k*132 + tc*8];
            float4 b1 = *(float4*)&bst[k*132 + tc*8 + 4];
            float ar[8] = {a0.x,a0.y,a0.z,a0.w,a1.x,a1.y,a1.z,a1.w};
            float br[8] = {b0.x,b0.y,b0.z,b0.w,b1.x,b1.y,b1.z,b1.w};
            #pragma unroll
            for (int i = 0; i < 8; ++i)
                #pragma unroll
                for (int j = 0; j < 8; ++j)
                    acc[i][j] += ar[i]*br[j];
        }
        __syncthreads();
    }
    float bcol[8];
    #pragma unroll
    for (int j = 0; j < 8; ++j) bcol[j] = bf1[cb*128 + tc*8 + j];
    #pragma unroll
    for (int i = 0; i < 8; ++i) {
        int row = r0 + tr*8 + i;
        if (row < NN) {
            float o[8];
            #pragma unroll
            for (int j = 0; j < 8; ++j) {
                float hv = acc[i][j] + bcol[j];
                o[j] = 0.5f*hv*(1.0f + erff(hv*0.7071067811865476f));
            }
            float4 o0 = make_float4(o[0],o[1],o[2],o[3]);
            float4 o1 = make_float4(o[4],o[5],o[6],o[7]);
            *(float4*)&h[(size_t)row*FD + cb*128 + tc*8]     = o0;
            *(float4*)&h[(size_t)row*FD + cb*128 + tc*8 + 4] = o1;
        }
    }
}

// ---------------- FFN2: h @ W2 + bf2 + LN1(y), LN2 stats -> d_out ----------------
__global__ __launch_bounds__(256) void ffn2_gemm(
    const float* __restrict__ h, const float* __restrict__ W2, const float* __restrict__ bf2,
    const float* __restrict__ y, const float* __restrict__ lng, const float* __restrict__ lnb,
    double* __restrict__ red, float* __restrict__ outz)
{
    __shared__ float ast[32*132];
    __shared__ float bst[32*132];
    const int tid = threadIdx.x;
    const int r0 = blockIdx.x * 128;
    double m = red[0] * (1.0/NCF);
    double var = red[1] * (1.0/NCF) - m*m;
    if (var < 0.0) var = 0.0;
    const float mean = (float)m;
    const float scale = (float)(1.0 / (sqrt(var) + 1e-5));
    const int tc = tid & 15, tr = tid >> 4;
    float acc[8][8];
    #pragma unroll
    for (int i = 0; i < 8; ++i)
        #pragma unroll
        for (int j = 0; j < 8; ++j) acc[i][j] = 0.f;

    for (int kc = 0; kc < 16; ++kc) {
        #pragma unroll
        for (int it = 0; it < 4; ++it) {
            int chunk = it*256 + tid;
            int row = chunk >> 3, c4 = chunk & 7;
            float4 g = make_float4(0.f,0.f,0.f,0.f);
            if (r0 + row < NN) g = ld4(&h[(size_t)(r0+row)*FD + kc*32 + c4*4]);
            ast[(c4*4+0)*132 + row] = g.x;
            ast[(c4*4+1)*132 + row] = g.y;
            ast[(c4*4+2)*132 + row] = g.z;
            ast[(c4*4+3)*132 + row] = g.w;
        }
        #pragma unroll
        for (int it = 0; it < 4; ++it) {
            int chunk = it*256 + tid;
            int kr = chunk >> 5, c4 = chunk & 31;
            *(float4*)&bst[kr*132 + c4*4] = ld4(&W2[(size_t)(kc*32+kr)*CD + c4*4]);
        }
        __syncthreads();
        #pragma unroll
        for (int k = 0; k < 32; ++k) {
            float4 a0 = *(float4*)&ast[k*132 + tr*8];
            float4 a1 = *(float4*)&ast[k*132 + tr*8 + 4];
            float4 b0 = *(float4*)&bst[k*132 + tc*8];
            float4 b1 = *(float4*)&bst[k*132 + tc*8 + 4];
            float ar[8] = {a0.x,a0.y,a0.z,a0.w,a1.x,a1.y,a1.z,a1.w};
            float br[8] = {b0.x,b0.y,b0.z,b0.w,b1.x,b1.y,b1.z,b1.w};
            #pragma unroll
            for (int i = 0; i < 8; ++i)
                #pragma unroll
                for (int j = 0; j < 8; ++j)
                    acc[i][j] += ar[i]*br[j];
        }
        __syncthreads();
    }
    float g1c[8], b1c[8], bfc[8];
    #pragma unroll
    for (int j = 0; j < 8; ++j) {
        int col = tc*8 + j;
        g1c[j] = lng[col]; b1c[j] = lnb[col]; bfc[j] = bf2[col];
    }
    float lsum = 0.f, lsq = 0.f;
    #pragma unroll
    for (int i = 0; i < 8; ++i) {
        int row = r0 + tr*8 + i;
        if (row < NN) {
            float4 ya = ld4(&y[row*CD + tc*8]);
            float4 yb = ld4(&y[row*CD + tc*8 + 4]);
            float yv[8] = {ya.x,ya.y,ya.z,ya.w,yb.x,yb.y,yb.z,yb.w};
            float z[8];
            #pragma unroll
            for (int j = 0; j < 8; ++j) {
                float x1 = (yv[j] - mean)*scale*g1c[j] + b1c[j];
                z[j] = acc[i][j] + bfc[j] + x1;
                lsum += z[j]; lsq += z[j]*z[j];
            }
            float4 z0 = make_float4(z[0],z[1],z[2],z[3]);
            float4 z1 = make_float4(z[4],z[5],z[6],z[7]);
            *(float4*)&outz[row*CD + tc*8]     = z0;
            *(float4*)&outz[row*CD + tc*8 + 4] = z1;
        }
    }
    #pragma unroll
    for (int off = 32; off; off >>= 1) {
        lsum += __shfl_xor(lsum, off);
        lsq  += __shfl_xor(lsq,  off);
    }
    if ((threadIdx.x & 63) == 0) {
        atomicAdd(&red[2], (double)lsum);
        atomicAdd(&red[3], (double)lsq);
    }
}

// ---------------- LN2 in-place on d_out ----------------
__global__ __launch_bounds__(256) void ln2_kernel(
    float* __restrict__ z, const float* __restrict__ g2, const float* __restrict__ b2,
    const double* __restrict__ red)
{
    double m = red[2] * (1.0/NCF);
    double var = red[3] * (1.0/NCF) - m*m;
    if (var < 0.0) var = 0.0;
    const float mean = (float)m;
    const float scale = (float)(1.0 / (sqrt(var) + 1e-5));
    const int stride = gridDim.x * blockDim.x;
    for (int i = blockIdx.x*blockDim.x + threadIdx.x; i < NN*32; i += stride) {
        int c4 = (i & 31) * 4;
        float4 zv = *(float4*)&z[(size_t)i*4];
        float4 gv = ld4(&g2[c4]);
        float4 bv = ld4(&b2[c4]);
        zv.x = (zv.x - mean)*scale*gv.x + bv.x;
        zv.y = (zv.y - mean)*scale*gv.y + bv.y;
        zv.z = (zv.z - mean)*scale*gv.z + bv.z;
        zv.w = (zv.w - mean)*scale*gv.w + bv.w;
        *(float4*)&z[(size_t)i*4] = zv;
    }
}

extern "C" void kernel_launch(void* const* d_in, const int* in_sizes, int n_in,
                              void* d_out, int out_size, void* d_ws, size_t ws_size,
                              hipStream_t stream) {
    const float* x     = (const float*)d_in[0];
    const float* ea    = (const float*)d_in[1];
    const int*   ei    = (const int*)d_in[2];      // integers arrive as int32
    const float* Wq    = (const float*)d_in[3];
    const float* bq    = (const float*)d_in[4];
    const float* Wk    = (const float*)d_in[5];
    const float* bk    = (const float*)d_in[6];
    const float* Wv    = (const float*)d_in[7];
    const float* bv    = (const float*)d_in[8];
    const float* We    = (const float*)d_in[9];
    const float* Wsk   = (const float*)d_in[10];
    const float* bsk   = (const float*)d_in[11];
    const float* Wbeta = (const float*)d_in[12];
    const float* g1v   = (const float*)d_in[13];
    const float* be1   = (const float*)d_in[14];
    const float* g2v   = (const float*)d_in[15];
    const float* be2   = (const float*)d_in[16];
    const float* W1    = (const float*)d_in[17];
    const float* bf1   = (const float*)d_in[18];
    const float* W2    = (const float*)d_in[19];
    const float* bf2   = (const float*)d_in[20];

    float* wsf = (float*)d_ws;
    float* q    = wsf;                  // [0, 6.4M)  dead after alpha; reused as y
    float* kk   = wsf +  6400000;       // dead after alpha; h[0]
    float* vv   = wsf + 12800000;       // dead after node;  h[1]
    float* xr   = wsf + 19200000;       // dead after combine; h[2]
    float* oa   = wsf + 25600000;       // dead after combine; h[3]
    float* a4   = wsf + 32000000;       // [32.0M, 34.4M) per-edge exp scores
    int*   off  = (int*)(wsf + 34400000);  // 50001 ints
    int*   cur  = off + 50001;             // 50000 ints (histogram counts -> scatter cursor)
    int*   elist= cur + 50000;             // 600000 ints
    double* red = (double*)(wsf + 35100056); // 8B-aligned (offset*4 = 140,400,224 % 8 == 0)
    float* y = q;
    float* h = kk;                      // h spans [6.4M, 32.0M) = N*512 floats
    float* zout = (float*)d_out;

    (void)hipMemsetAsync(cur, 0, 50000*sizeof(int), stream);
    (void)hipMemsetAsync(red, 0, 4*sizeof(double), stream);

    // CSR build
    hist_kernel<<<(EE+255)/256, 256, 0, stream>>>(ei, cur);
    scan_kernel<<<1, 256, 0, stream>>>(cur, off);
    scatter_kernel<<<(EE+255)/256, 256, 0, stream>>>(ei, cur, elist);

    dim3 gA((NN + 127)/128, 4);
    qkvs_gemm<<<gA, 256, 0, stream>>>(x, Wq,bq, Wk,bk, Wv,bv, Wsk,bsk, q, kk, vv, xr);

    alpha_kernel<<<(EE + 127)/128, 256, 0, stream>>>(ea, ei, We, q, kk, a4);

    node_kernel<<<(NN + 3)/4, 256, 0, stream>>>(ei, off, elist, a4, ea, vv, We, oa);

    combine_kernel<<<1024, 256, 0, stream>>>(x, xr, oa, Wbeta, y, red);

    dim3 gF((NN + 127)/128, 4);
    ffn1_gemm<<<gF, 256, 0, stream>>>(y, W1, bf1, g1v, be1, red, h);

    ffn2_gemm<<<(NN + 127)/128, 256, 0, stream>>>(h, W2, bf2, y, g1v, be1, red, zout);

    ln2_kernel<<<2048, 256, 0, stream>>>(zout, g2v, be2, red);
}